// Round 5
// baseline (3745.857 us; speedup 1.0000x reference)
//
#include <hip/hip_runtime.h>
#include <hip/hip_bf16.h>

typedef _Float16 fp16_t;
typedef _Float16 v8h __attribute__((ext_vector_type(8)));
typedef _Float16 v4h __attribute__((ext_vector_type(4)));
typedef float    v4f __attribute__((ext_vector_type(4)));

#define RELAX_LR 0.3f

// async global->LDS, 16B per lane. LDS dest = wave-uniform base + lane*16.
__device__ __forceinline__ void async_cp16(const void* g, void* l) {
    __builtin_amdgcn_global_load_lds(
        (const __attribute__((address_space(1))) void*)g,
        (__attribute__((address_space(3))) void*)l, 16, 0, 0);
}

// ---------------------------------------------------------------------------
// Split-K GEMM into fp32 partials.
// Concatenated K-space [0,K1) -> A1*B1t^T, [K1,K1+K2s) -> A2*B2t^T; block z
// owns K-chunk [z*CK,(z+1)*CK) (never crosses K1 by launch construction).
// Tile BM=64 x BN=128 x BK=32, 256 thr = 4 waves, each wave a 32x64 tile of
// 2x4 16x16x32 f16 MFMAs. Double-buffered LDS (24 KB), one barrier/K-iter:
// async stage(k+1) overlaps MFMA(k). 4 blocks/CU target.
// ---------------------------------------------------------------------------
__global__ __launch_bounds__(256, 4) void gemm_splitk_kernel(
    const fp16_t* __restrict__ A1, const fp16_t* __restrict__ B1t, int K1,
    const fp16_t* __restrict__ A2, const fp16_t* __restrict__ B2t, int K2s,
    int CK, float* __restrict__ part, int Ntot)
{
    __shared__ __align__(16) fp16_t As[2][64][32];
    __shared__ __align__(16) fp16_t Bs[2][128][32];

    const int tid  = threadIdx.x;
    const int lane = tid & 63;
    const int w    = tid >> 6;         // wave 0..3
    const int wm   = w >> 1;           // row-half (32 rows)
    const int wn   = w & 1;            // col-half (64 cols)
    const int quad = lane >> 4;
    const int lrow = lane & 15;
    const int bm = blockIdx.y, bn = blockIdx.x, z = blockIdx.z;

    int koff = z * CK;
    const fp16_t* A; const fp16_t* Bt; int stride;
    if (koff < K1) { A = A1; Bt = B1t; stride = K1; }
    else           { A = A2; Bt = B2t; stride = K2s; koff -= K1; }

    // staging: lane -> (row = base + lane/4, col = (lane&3)*8); each inst = 1KB
    // = 16 rows of 32 fp16. Wave w: A rows [16w,16w+16), B rows [32w,32w+32).
    const int sr = lane >> 2;
    const int sc = (lane & 3) * 8;
    const fp16_t* ag = A  + (size_t)(bm * 64  + 16 * w + sr) * stride + koff + sc;
    const fp16_t* bg = Bt + (size_t)(bn * 128 + 32 * w + sr) * stride + koff + sc;
    const size_t step16 = (size_t)16 * stride;

    v4f acc[2][4] = {};

    const int iters = CK >> 5;

    // prologue: stage tile 0 into buffer 0
    async_cp16(ag,          &As[0][16 * w     ][0]);
    async_cp16(bg,          &Bs[0][32 * w     ][0]);
    async_cp16(bg + step16, &Bs[0][32 * w + 16][0]);
    ag += 32; bg += 32;

    for (int it = 0; it < iters; ++it) {
        __syncthreads();   // drains vmcnt -> buf (it&1) ready; prior ds_reads done
        if (it + 1 < iters) {
            const int nb = (it + 1) & 1;
            async_cp16(ag,          &As[nb][16 * w     ][0]);
            async_cp16(bg,          &Bs[nb][32 * w     ][0]);
            async_cp16(bg + step16, &Bs[nb][32 * w + 16][0]);
            ag += 32; bg += 32;
        }
        const int cur = it & 1;
        v8h af[2], bv[4];
        #pragma unroll
        for (int fm = 0; fm < 2; ++fm)
            af[fm] = *(const v8h*)&As[cur][wm * 32 + fm * 16 + lrow][quad * 8];
        #pragma unroll
        for (int fn = 0; fn < 4; ++fn)
            bv[fn] = *(const v8h*)&Bs[cur][wn * 64 + fn * 16 + lrow][quad * 8];
        #pragma unroll
        for (int fm = 0; fm < 2; ++fm)
            #pragma unroll
            for (int fn = 0; fn < 4; ++fn)
                acc[fm][fn] = __builtin_amdgcn_mfma_f32_16x16x32_f16(
                    af[fm], bv[fn], acc[fm][fn], 0, 0, 0);
    }

    // write fp32 partials. C/D layout: col = lane&15, row = quad*4 + reg.
    float* po = part + (size_t)z * 1024 * Ntot;
    const int rowbase = bm * 64 + wm * 32 + quad * 4;
    const int colbase = bn * 128 + wn * 64;
    #pragma unroll
    for (int fn = 0; fn < 4; ++fn) {
        const int col = colbase + fn * 16 + lrow;
        #pragma unroll
        for (int fm = 0; fm < 2; ++fm) {
            const int row = rowbase + fm * 16;
            #pragma unroll
            for (int r = 0; r < 4; ++r)
                po[(size_t)(row + r) * Ntot + col] = acc[fm][fn][r];
        }
    }
}

// ---------------------------------------------------------------------------
// Sum nz partials + bias, then init/update + clip, dual-precision state write.
// 4 elements per thread, float4 loads. Ntot is a power of two.
// ---------------------------------------------------------------------------
__global__ __launch_bounds__(256) void reduce_update_kernel(
    const float* __restrict__ part, int nz,
    const float* __restrict__ bias, const float* __restrict__ s_old,
    float* __restrict__ outf, fp16_t* __restrict__ outb,
    int Ntot, int do_update, int total4)
{
    const int i = blockIdx.x * 256 + threadIdx.x;
    if (i >= total4) return;
    const size_t e = (size_t)i * 4;

    float4 a = *(const float4*)(part + e);
    for (int z = 1; z < nz; ++z) {
        const float4 p = *(const float4*)(part + (size_t)z * 1024 * Ntot + e);
        a.x += p.x; a.y += p.y; a.z += p.z; a.w += p.w;
    }
    const int col = (int)e & (Ntot - 1);
    const float4 bv = *(const float4*)(bias + col);
    float v[4] = {a.x + bv.x, a.y + bv.y, a.z + bv.z, a.w + bv.w};
    if (do_update) {
        const float4 so = *(const float4*)(s_old + e);
        v[0] = so.x + RELAX_LR * (v[0] - so.x);
        v[1] = so.y + RELAX_LR * (v[1] - so.y);
        v[2] = so.z + RELAX_LR * (v[2] - so.z);
        v[3] = so.w + RELAX_LR * (v[3] - so.w);
    }
    float4 o;
    o.x = fminf(fmaxf(v[0], 0.f), 1.f);
    o.y = fminf(fmaxf(v[1], 0.f), 1.f);
    o.z = fminf(fmaxf(v[2], 0.f), 1.f);
    o.w = fminf(fmaxf(v[3], 0.f), 1.f);
    *(float4*)(outf + e) = o;
    v4h h = {(fp16_t)o.x, (fp16_t)o.y, (fp16_t)o.z, (fp16_t)o.w};
    *(v4h*)(outb + e) = h;
}

// fp32 W [R,C] -> fp16 Wb [Rp,Cp] (optional) + fp16 WbT [Cp,Rp], zero-padded.
__global__ void conv_w_kernel(const float* __restrict__ W, int R, int C,
                              fp16_t* Wb, fp16_t* __restrict__ WbT,
                              int Rp, int Cp)
{
    __shared__ float t[32][33];
    const int tx = threadIdx.x & 31;
    const int ty = threadIdx.x >> 5;   // 0..7
    const int r0 = blockIdx.y * 32;
    const int c0 = blockIdx.x * 32;
    #pragma unroll
    for (int i = 0; i < 4; ++i) {
        const int r = r0 + ty + i * 8;
        const int c = c0 + tx;
        float v = 0.f;
        if (r < R && c < C) v = W[(size_t)r * C + c];
        t[ty + i * 8][tx] = v;
    }
    __syncthreads();
    if (Wb) {
        #pragma unroll
        for (int i = 0; i < 4; ++i) {
            const int r = r0 + ty + i * 8;
            const int c = c0 + tx;
            if (r < Rp && c < Cp) Wb[(size_t)r * Cp + c] = (fp16_t)t[ty + i * 8][tx];
        }
    }
    #pragma unroll
    for (int i = 0; i < 4; ++i) {
        const int cc = c0 + ty + i * 8;
        const int rr = r0 + tx;
        if (cc < Cp && rr < Rp) WbT[(size_t)cc * Rp + rr] = (fp16_t)t[tx][ty + i * 8];
    }
}

__global__ void conv_x_kernel(const float* __restrict__ x,
                              fp16_t* __restrict__ xb, fp16_t* __restrict__ rxb, int n)
{
    const int i = blockIdx.x * blockDim.x + threadIdx.x;
    if (i < n) {
        const float v = x[i];
        xb[i]  = (fp16_t)v;
        rxb[i] = (fp16_t)fminf(fmaxf(v, 0.f), 1.f);
    }
}

__global__ void pad_b4_kernel(const float* __restrict__ b4, float* __restrict__ b4p)
{
    const int i = blockIdx.x * blockDim.x + threadIdx.x;
    if (i < 1024) b4p[i] = (i < 1000) ? b4[i] : 0.f;
}

__global__ void out_copy_kernel(const float* __restrict__ s4f, float* __restrict__ out)
{
    const int i = blockIdx.x * blockDim.x + threadIdx.x;
    if (i < 1024 * 1000) {
        const int row = i / 1000;
        const int col = i - row * 1000;
        out[i] = s4f[(size_t)row * 1024 + col];
    }
}

extern "C" void kernel_launch(void* const* d_in, const int* in_sizes, int n_in,
                              void* d_out, int out_size, void* d_ws, size_t ws_size,
                              hipStream_t stream)
{
    const float* x  = (const float*)d_in[0];
    const float* W0 = (const float*)d_in[1];
    const float* W1 = (const float*)d_in[2];
    const float* W2 = (const float*)d_in[3];
    const float* W3 = (const float*)d_in[4];
    const float* b1 = (const float*)d_in[5];
    const float* b2 = (const float*)d_in[6];
    const float* b3 = (const float*)d_in[7];
    const float* b4 = (const float*)d_in[8];
    float* out = (float*)d_out;

    char* p = (char*)d_ws;
    auto alloc = [&](size_t bytes) {
        char* q = p;
        p += (bytes + 255) & ~(size_t)255;
        return q;
    };

    fp16_t* xb   = (fp16_t*)alloc((size_t)1024 * 2048 * 2);
    fp16_t* rxb  = (fp16_t*)alloc((size_t)1024 * 2048 * 2);
    fp16_t* Wb1  = (fp16_t*)alloc((size_t)2048 * 2048 * 2);
    fp16_t* Wb2  = (fp16_t*)alloc((size_t)2048 * 2048 * 2);
    fp16_t* Wb3  = (fp16_t*)alloc((size_t)2048 * 1024 * 2);   // padded cols
    fp16_t* WbT0 = (fp16_t*)alloc((size_t)2048 * 2048 * 2);
    fp16_t* WbT1 = (fp16_t*)alloc((size_t)2048 * 2048 * 2);
    fp16_t* WbT2 = (fp16_t*)alloc((size_t)2048 * 2048 * 2);
    fp16_t* WbT3 = (fp16_t*)alloc((size_t)1024 * 2048 * 2);   // padded rows
    float*  s1f  = (float*)alloc((size_t)1024 * 2048 * 4);
    float*  s2f  = (float*)alloc((size_t)1024 * 2048 * 4);
    float*  s3f  = (float*)alloc((size_t)1024 * 2048 * 4);
    float*  s4f  = (float*)alloc((size_t)1024 * 1024 * 4);
    fp16_t* s1b  = (fp16_t*)alloc((size_t)1024 * 2048 * 2);
    fp16_t* s2b  = (fp16_t*)alloc((size_t)1024 * 2048 * 2);
    fp16_t* s3b  = (fp16_t*)alloc((size_t)1024 * 2048 * 2);
    fp16_t* s4b  = (fp16_t*)alloc((size_t)1024 * 1024 * 2);
    float*  b4p  = (float*)alloc(1024 * 4);
    float*  part = (float*)alloc((size_t)4 * 1024 * 2048 * 4); // 32 MB, reused
    (void)ws_size; (void)in_sizes; (void)n_in; (void)out_size;

    // --- setup conversions ---
    conv_x_kernel<<<(1024 * 2048 + 255) / 256, 256, 0, stream>>>(x, xb, rxb, 1024 * 2048);
    pad_b4_kernel<<<4, 256, 0, stream>>>(b4, b4p);
    conv_w_kernel<<<dim3(64, 64), 256, 0, stream>>>(W0, 2048, 2048, nullptr, WbT0, 2048, 2048);
    conv_w_kernel<<<dim3(64, 64), 256, 0, stream>>>(W1, 2048, 2048, Wb1, WbT1, 2048, 2048);
    conv_w_kernel<<<dim3(64, 64), 256, 0, stream>>>(W2, 2048, 2048, Wb2, WbT2, 2048, 2048);
    conv_w_kernel<<<dim3(32, 64), 256, 0, stream>>>(W3, 2048, 1000, Wb3, WbT3, 2048, 1024);

    const dim3 blk(256);
    const int t4_2048 = 1024 * 2048 / 4;
    const int t4_1024 = 1024 * 1024 / 4;
    const int rg2048 = t4_2048 / 256;
    const int rg1024 = t4_1024 / 256;

    // BM=64 -> grid.y = 16. Layers 1-3 (N=2048): grid.x = 16. Layer 4: 8.
    // --- feedforward init (single GEMM, K=2048) ---
    gemm_splitk_kernel<<<dim3(16, 16, 4), blk, 0, stream>>>(xb,  WbT0, 2048, nullptr, nullptr, 0, 512, part, 2048);
    reduce_update_kernel<<<rg2048, blk, 0, stream>>>(part, 4, b1, nullptr, s1f, s1b, 2048, 0, t4_2048);
    gemm_splitk_kernel<<<dim3(16, 16, 4), blk, 0, stream>>>(s1b, WbT1, 2048, nullptr, nullptr, 0, 512, part, 2048);
    reduce_update_kernel<<<rg2048, blk, 0, stream>>>(part, 4, b2, nullptr, s2f, s2b, 2048, 0, t4_2048);
    gemm_splitk_kernel<<<dim3(16, 16, 4), blk, 0, stream>>>(s2b, WbT2, 2048, nullptr, nullptr, 0, 512, part, 2048);
    reduce_update_kernel<<<rg2048, blk, 0, stream>>>(part, 4, b3, nullptr, s3f, s3b, 2048, 0, t4_2048);
    gemm_splitk_kernel<<<dim3(8, 16, 8), blk, 0, stream>>>(s3b, WbT3, 2048, nullptr, nullptr, 0, 256, part, 1024);
    reduce_update_kernel<<<rg1024, blk, 0, stream>>>(part, 8, b4p, nullptr, s4f, s4b, 1024, 0, t4_1024);

    // --- 25 Gauss-Seidel sweeps (states post-rho => rho identity on them) ---
    for (int it = 0; it < 25; ++it) {
        // layer 1: rho(x)@W0 + s2@W1^T   (K-space 2048+2048, CK=1024, z=4)
        gemm_splitk_kernel<<<dim3(16, 16, 4), blk, 0, stream>>>(rxb, WbT0, 2048, s2b, Wb1, 2048, 1024, part, 2048);
        reduce_update_kernel<<<rg2048, blk, 0, stream>>>(part, 4, b1, s1f, s1f, s1b, 2048, 1, t4_2048);
        // layer 2: s1@W1 + s3@W2^T
        gemm_splitk_kernel<<<dim3(16, 16, 4), blk, 0, stream>>>(s1b, WbT1, 2048, s3b, Wb2, 2048, 1024, part, 2048);
        reduce_update_kernel<<<rg2048, blk, 0, stream>>>(part, 4, b2, s2f, s2f, s2b, 2048, 1, t4_2048);
        // layer 3: s2@W2 + s4@W3^T (K2=1024, CK=1024, z=3)
        gemm_splitk_kernel<<<dim3(16, 16, 3), blk, 0, stream>>>(s2b, WbT2, 2048, s4b, Wb3, 1024, 1024, part, 2048);
        reduce_update_kernel<<<rg2048, blk, 0, stream>>>(part, 3, b3, s3f, s3f, s3b, 2048, 1, t4_2048);
        // layer 4: s3@W3 (K=2048, CK=256, z=8)
        gemm_splitk_kernel<<<dim3(8, 16, 8), blk, 0, stream>>>(s3b, WbT3, 2048, nullptr, nullptr, 0, 256, part, 1024);
        reduce_update_kernel<<<rg1024, blk, 0, stream>>>(part, 8, b4p, s4f, s4f, s4b, 1024, 1, t4_1024);
    }

    // --- strip padding into d_out [1024,1000] ---
    out_copy_kernel<<<(1024 * 1000 + 255) / 256, 256, 0, stream>>>(s4f, out);
}